// Round 7
// baseline (19682.088 us; speedup 1.0000x reference)
//
#include <hip/hip_runtime.h>
#include <hip/hip_bf16.h>

#define B_ 64
#define T_ 1024
#define D_ 512
#define H_ 512
#define O_ 512
#define NBLK 32            // lstm blocks
#define NWORK 224          // out_proj worker blocks
#define FLG_ZERO_N 128     // flg[0..31] step flags, flg[64] progress

using bf16x8 = __attribute__((ext_vector_type(8))) short;
using f32x4  = __attribute__((ext_vector_type(4))) float;
using u32x4  = __attribute__((ext_vector_type(4))) unsigned int;

__device__ __forceinline__ short f2bfs(float f) {
  return (short)__builtin_bit_cast(unsigned short, __float2bfloat16(f));
}
__device__ __forceinline__ float sigmoid_f(float v) {
  return 1.0f / (1.0f + __expf(-v));
}
__device__ __forceinline__ float tanh_f(float v) {
  float a = fabsf(v);
  float e = __expf(-2.0f * a);
  float t = (1.0f - e) / (1.0f + e);
  return copysignf(t, v);
}

// ---------------------------------------------------------------------------
// Setup: pack W_all (1024x2048) and W_hy (512x512) into MFMA B-fragment order
// (bf16), convert h_init to bf16, zero flags + progress.
// ---------------------------------------------------------------------------
__global__ __launch_bounds__(256) void pack_setup(
    const float* __restrict__ Wf, const float* __restrict__ Wi,
    const float* __restrict__ Wc, const float* __restrict__ Wo,
    const float* __restrict__ Why, const float* __restrict__ hinit,
    unsigned short* __restrict__ Wp, unsigned short* __restrict__ Whyp,
    unsigned short* __restrict__ hbf0, unsigned int* __restrict__ flg)
{
  long idx = (long)blockIdx.x * blockDim.x + threadIdx.x;
  if (idx < FLG_ZERO_N) flg[idx] = 0u;         // re-zeroed every call
  const long NW = 1024L * 2048;
  const long NY = 512L * 512;
  const long NH = 64L * 512;
  if (idx < NW) {
    int e = idx & 7, l = (idx >> 3) & 63, kk = (idx >> 9) & 31;
    int Jc = (int)(idx >> 14);                   // 0..127
    int k = kk * 32 + (l >> 4) * 8 + e;          // 0..1023
    int col = Jc * 16 + (l & 15);                // 0..2047
    int gg = col >> 9, j = col & 511;
    const float* W = (gg == 0) ? Wf : (gg == 1) ? Wi : (gg == 2) ? Wc : Wo;
    Wp[idx] = (unsigned short)f2bfs(W[(long)k * 512 + j]);
  } else if (idx < NW + NY) {
    long q = idx - NW;
    int e = q & 7, l = (q >> 3) & 63, kk = (q >> 9) & 15;
    int J = (int)(q >> 13);
    int k = kk * 32 + (l >> 4) * 8 + e;
    int col = J * 16 + (l & 15);
    Whyp[q] = (unsigned short)f2bfs(Why[(long)k * 512 + col]);
  } else if (idx < NW + NY + NH) {
    long q = idx - NW - NY;
    hbf0[q] = (unsigned short)f2bfs(hinit[q]);
  }
}

// ---------------------------------------------------------------------------
// x fp32 -> bf16 streaming conversion.
// ---------------------------------------------------------------------------
__global__ __launch_bounds__(256) void xconv(
    const float* __restrict__ x, unsigned short* __restrict__ xb)
{
  long i = ((long)blockIdx.x * 256 + threadIdx.x) * 8;
  float4 a = *(const float4*)(x + i);
  float4 b = *(const float4*)(x + i + 4);
  bf16x8 v;
  v[0] = f2bfs(a.x); v[1] = f2bfs(a.y); v[2] = f2bfs(a.z); v[3] = f2bfs(a.w);
  v[4] = f2bfs(b.x); v[5] = f2bfs(b.y); v[6] = f2bfs(b.z); v[7] = f2bfs(b.w);
  *(bf16x8*)(xb + i) = v;
}

// ---------------------------------------------------------------------------
// Fused kernel, 256 blocks x 256 threads, 1 block/CU (VGPR>256 via ballast).
// Blocks 0..31:  round-4 proven recurrence (sc0 sc1, wave0 busy-poll).
//   - hs stores moved BEFORE the drain barrier (flags now certify hs)
//   - block 0 publishes `progress` = t after its poll (hs rows < t valid)
// Blocks 32..255: out_proj workers. Worker wk owns timesteps t = wk + 224k.
//   Wait for progress >= t+1 while burning dependent FMAs (keeps clocks up,
//   zero memory traffic), then compute out[:, t, :] = hs[t] @ W_hy + b_hy.
//   hs read with sc0 sc1 loads (fresh across XCDs and graph replays).
// ---------------------------------------------------------------------------
template<bool X16>
__global__ __attribute__((amdgpu_waves_per_eu(1, 1))) __launch_bounds__(256)
void lstm_fused(
    const void* __restrict__ xv,      // (B,T,D) bf16 or fp32
    const float* __restrict__ cinit,  // (B,H)
    const float* __restrict__ bf_, const float* __restrict__ bi_,
    const float* __restrict__ bc_, const float* __restrict__ bo_,
    const unsigned short* __restrict__ Wp,
    const unsigned short* __restrict__ Whyp,
    const float* __restrict__ bhy,
    unsigned short* __restrict__ hbf0,
    unsigned short* __restrict__ hbf1,
    unsigned short* __restrict__ hs,  // (T,B,H) bf16
    float* __restrict__ out,          // (B,T,O) + tail
    unsigned int* __restrict__ flg)
{
  const int bid  = blockIdx.x;
  const int tid  = threadIdx.x;
  const int wv   = tid >> 6;
  const int lane = tid & 63;
  const int lrow = lane & 15;
  const int lkg  = lane >> 4;

  // VGPR ballast: force >256 VGPR -> 1 wave/SIMD -> 1 block/CU.
  f32x4 pad[16];
  #pragma unroll
  for (int i = 0; i < 16; ++i) pad[i] = {0.f, 0.f, 0.f, 0.f};
  #define KEEPPADS() do { \
    asm volatile("" : "+v"(pad[0]), "+v"(pad[1]), "+v"(pad[2]), "+v"(pad[3])); \
    asm volatile("" : "+v"(pad[4]), "+v"(pad[5]), "+v"(pad[6]), "+v"(pad[7])); \
    asm volatile("" : "+v"(pad[8]), "+v"(pad[9]), "+v"(pad[10]), "+v"(pad[11])); \
    asm volatile("" : "+v"(pad[12]), "+v"(pad[13]), "+v"(pad[14]), "+v"(pad[15])); \
  } while (0)

  unsigned int* prog = flg + 64;
  float* tail = out + (size_t)B_ * T_ * O_;

  if (bid < NBLK) {
    // ===================== LSTM recurrence (round-4 proven path) ============
    const int jb = bid;
    const int b_arow = wv * 16 + lrow;
    const int jcol   = jb * 16 + lrow;
    const int b_cd0  = wv * 16 + lkg * 4;

    const float vbf = bf_[jcol], vbi = bi_[jcol], vbc = bc_[jcol], vbo = bo_[jcol];
    float c0 = cinit[(long)(b_cd0 + 0) * H_ + jcol];
    float c1 = cinit[(long)(b_cd0 + 1) * H_ + jcol];
    float c2 = cinit[(long)(b_cd0 + 2) * H_ + jcol];
    float c3 = cinit[(long)(b_cd0 + 3) * H_ + jcol];

    const long aq = (long)b_arow * 128 + lkg * 2;
    const unsigned short* xrow16 = X16 ? (const unsigned short*)xv + (long)b_arow * T_ * D_ + lkg * 8 : nullptr;
    const float*          xrow32 = X16 ? nullptr : (const float*)xv + (long)b_arow * T_ * D_ + lkg * 8;
    const unsigned short* w0 = Wp + (long)(0 * 32 + jb) * 32 * 512 + lane * 8;
    const unsigned short* w1 = Wp + (long)(1 * 32 + jb) * 32 * 512 + lane * 8;
    const unsigned short* w2 = Wp + (long)(2 * 32 + jb) * 32 * 512 + lane * 8;
    const unsigned short* w3 = Wp + (long)(3 * 32 + jb) * 32 * 512 + lane * 8;
    const unsigned long long* h0q = (const unsigned long long*)hbf0;
    const unsigned long long* h1q = (const unsigned long long*)hbf1;

    bf16x8 xf[16];
    float4 xr[32];
    if constexpr (X16) {
      #pragma unroll
      for (int kk = 0; kk < 16; ++kk) xf[kk] = *(const bf16x8*)(xrow16 + kk * 32);
    } else {
      #pragma unroll
      for (int kk = 0; kk < 16; ++kk) {
        xr[2*kk]   = *(const float4*)(xrow32 + kk * 32);
        xr[2*kk+1] = *(const float4*)(xrow32 + kk * 32 + 4);
      }
    }

    #pragma unroll 1
    for (int t = 0; t < T_; ++t) {
      KEEPPADS();
      // x half of GEMM (k 512..1023) before the poll
      f32x4 af = {vbf, vbf, vbf, vbf};
      f32x4 ai = {vbi, vbi, vbi, vbi};
      f32x4 ac = {vbc, vbc, vbc, vbc};
      f32x4 ao = {vbo, vbo, vbo, vbo};
      #pragma unroll
      for (int kk = 0; kk < 16; ++kk) {
        bf16x8 ax;
        if constexpr (X16) {
          ax = xf[kk];
        } else {
          float4 xa = xr[2*kk], xb2 = xr[2*kk+1];
          ax[0]=f2bfs(xa.x); ax[1]=f2bfs(xa.y); ax[2]=f2bfs(xa.z); ax[3]=f2bfs(xa.w);
          ax[4]=f2bfs(xb2.x); ax[5]=f2bfs(xb2.y); ax[6]=f2bfs(xb2.z); ax[7]=f2bfs(xb2.w);
        }
        const int k2 = kk + 16;
        af = __builtin_amdgcn_mfma_f32_16x16x32_bf16(ax, *(const bf16x8*)(w0 + k2 * 512), af, 0, 0, 0);
        ai = __builtin_amdgcn_mfma_f32_16x16x32_bf16(ax, *(const bf16x8*)(w1 + k2 * 512), ai, 0, 0, 0);
        ac = __builtin_amdgcn_mfma_f32_16x16x32_bf16(ax, *(const bf16x8*)(w2 + k2 * 512), ac, 0, 0, 0);
        ao = __builtin_amdgcn_mfma_f32_16x16x32_bf16(ax, *(const bf16x8*)(w3 + k2 * 512), ao, 0, 0, 0);
      }

      // wave0 busy-poll (all-CU-busy keeps clocks high; detect ~1 round trip)
      if (wv == 0) {
        const unsigned tgt = (unsigned)t;
        const unsigned int* fp = flg + (lane & 31);
        int guard = 0;
        for (;;) {
          unsigned f;
          asm volatile("global_load_dword %0, %1, off sc0 sc1\n\ts_waitcnt vmcnt(0)"
                       : "=v"(f) : "v"(fp) : "memory");
          if (__all((int)(f >= tgt))) break;
          if (++guard > (1 << 17)) break;
        }
        // publish progress: all blocks finished step t-1 => hs rows < t valid
        if (jb == 0 && lane == 0) {
          unsigned pv = (unsigned)t;
          asm volatile("global_store_dword %0, %1, off sc0 sc1" :: "v"(prog), "v"(pv) : "memory");
        }
      }
      __syncthreads();
      asm volatile("" ::: "memory");

      // h loads (agent-coherent)
      const unsigned long long* hq = (t & 1) ? h1q : h0q;
      #pragma unroll
      for (int kk = 0; kk < 16; ++kk) {
        unsigned long long q0 = __hip_atomic_load(hq + aq + kk * 8,     __ATOMIC_RELAXED, __HIP_MEMORY_SCOPE_AGENT);
        unsigned long long q1 = __hip_atomic_load(hq + aq + kk * 8 + 1, __ATOMIC_RELAXED, __HIP_MEMORY_SCOPE_AGENT);
        union { unsigned long long q[2]; bf16x8 v; } u;
        u.q[0] = q0; u.q[1] = q1;
        bf16x8 ah = u.v;
        af = __builtin_amdgcn_mfma_f32_16x16x32_bf16(ah, *(const bf16x8*)(w0 + kk * 512), af, 0, 0, 0);
        ai = __builtin_amdgcn_mfma_f32_16x16x32_bf16(ah, *(const bf16x8*)(w1 + kk * 512), ai, 0, 0, 0);
        ac = __builtin_amdgcn_mfma_f32_16x16x32_bf16(ah, *(const bf16x8*)(w2 + kk * 512), ac, 0, 0, 0);
        ao = __builtin_amdgcn_mfma_f32_16x16x32_bf16(ah, *(const bf16x8*)(w3 + kk * 512), ao, 0, 0, 0);
      }

      // gates + state update (C/D: col=lane&15, row=(lane>>4)*4+i)
      unsigned short* hw = (t & 1) ? hbf0 : hbf1;
      float hvf[4], cvf[4];
      #pragma unroll
      for (int i2 = 0; i2 < 4; ++i2) {
        float fg = sigmoid_f(af[i2]);
        float ig = sigmoid_f(ai[i2]);
        float gg2 = tanh_f(ac[i2]);
        float og = sigmoid_f(ao[i2]);
        float cN = (i2 == 0) ? c0 : (i2 == 1) ? c1 : (i2 == 2) ? c2 : c3;
        cN = fg * cN + ig * gg2;
        float hv = og * tanh_f(cN);
        if (i2 == 0) c0 = cN; else if (i2 == 1) c1 = cN; else if (i2 == 2) c2 = cN; else c3 = cN;
        hvf[i2] = hv; cvf[i2] = cN;
        unsigned hb = (unsigned)(unsigned short)f2bfs(hv);
        int brow = b_cd0 + i2;
        // publish h_t (write-through, agent-visible)
        unsigned short* hp2 = hw + (long)brow * H_ + jcol;
        asm volatile("global_store_short %0, %1, off sc0 sc1" :: "v"(hp2), "v"(hb) : "memory");
        // hs history BEFORE the barrier so the flag certifies it
        unsigned short* hsp = hs + ((long)t * B_ + brow) * H_ + jcol;
        asm volatile("global_store_short %0, %1, off sc0 sc1" :: "v"(hsp), "v"(hb) : "memory");
      }

      // drain all publishes, then ONE flag store
      __syncthreads();
      asm volatile("" ::: "memory");
      if (tid == 0) {
        unsigned v = (unsigned)(t + 1);
        unsigned int* p2 = flg + jb;
        asm volatile("global_store_dword %0, %1, off sc0 sc1" :: "v"(p2), "v"(v) : "memory");
      }
      asm volatile("" ::: "memory");

      // off-critical-path: tail + next-x prefetch
      if (t == T_ - 1) {
        #pragma unroll
        for (int i2 = 0; i2 < 4; ++i2) {
          int brow = b_cd0 + i2;
          tail[(long)brow * H_ + jcol] = hvf[i2];
          tail[(long)B_ * H_ + (long)brow * H_ + jcol] = cvf[i2];
        }
      }
      const long tn = (t + 1 < T_) ? (t + 1) : t;
      if constexpr (X16) {
        const unsigned short* xt = xrow16 + tn * D_;
        #pragma unroll
        for (int kk = 0; kk < 16; ++kk) xf[kk] = *(const bf16x8*)(xt + kk * 32);
      } else {
        const float* xt = xrow32 + tn * D_;
        #pragma unroll
        for (int kk = 0; kk < 16; ++kk) {
          xr[2*kk]   = *(const float4*)(xt + kk * 32);
          xr[2*kk+1] = *(const float4*)(xt + kk * 32 + 4);
        }
      }
    }

    // epilogue: block 0 publishes final progress = T_
    if (jb == 0 && wv == 0) {
      const unsigned int* fp = flg + (lane & 31);
      int guard = 0;
      for (;;) {
        unsigned f;
        asm volatile("global_load_dword %0, %1, off sc0 sc1\n\ts_waitcnt vmcnt(0)"
                     : "=v"(f) : "v"(fp) : "memory");
        if (__all((int)(f >= (unsigned)T_)) || ++guard > (1 << 17)) break;
      }
      if (lane == 0) {
        unsigned pv = (unsigned)T_;
        asm volatile("global_store_dword %0, %1, off sc0 sc1" :: "v"(prog), "v"(pv) : "memory");
      }
    }
  } else {
    // ===================== out_proj workers =====================
    const int wk = bid - NBLK;     // 0..223
    float burn = (float)(tid + 1) * 1e-3f;

    #pragma unroll 1
    for (int t = wk; t < T_; t += NWORK) {
      KEEPPADS();
      // wait for progress >= t+1, burning FMAs (no memory traffic) meanwhile
      {
        int it = 0;
        for (;;) {
          unsigned p;
          asm volatile("global_load_dword %0, %1, off sc0 sc1\n\ts_waitcnt vmcnt(0)"
                       : "=v"(p) : "v"((const unsigned int*)prog) : "memory");
          if ((int)p >= t + 1 || ++it > (1 << 18)) break;
          int reps = ((t + 1 - (int)p) > 4) ? 8 : 1;
          #pragma unroll 1
          for (int r = 0; r < reps; ++r) {
            #pragma unroll
            for (int u = 0; u < 128; ++u) burn = burn * 1.0000002f + 1e-9f;
            asm volatile("" : "+v"(burn));
          }
        }
      }

      // A-frags: hs rows of timestep t (b = wv*16 + lrow), fresh sc1 loads
      const unsigned short* hsrow = hs + ((long)t * B_ + wv * 16 + lrow) * H_ + lkg * 8;
      u32x4 a[16];
      #pragma unroll
      for (int kk = 0; kk < 16; ++kk) {
        const unsigned short* pA = hsrow + kk * 32;
        asm volatile("global_load_dwordx4 %0, %1, off sc0 sc1" : "=v"(a[kk]) : "v"(pA));
      }
      asm volatile("s_waitcnt vmcnt(0)" ::: "memory");

      f32x4 acc[32];
      #pragma unroll
      for (int nt2 = 0; nt2 < 32; ++nt2) {
        float bb = bhy[nt2 * 16 + lrow];
        acc[nt2] = {bb, bb, bb, bb};
      }
      #pragma unroll
      for (int kk = 0; kk < 16; ++kk) {
        bf16x8 av = __builtin_bit_cast(bf16x8, a[kk]);
        #pragma unroll
        for (int nt2 = 0; nt2 < 32; ++nt2) {
          bf16x8 bv = *(const bf16x8*)(Whyp + ((long)(nt2 * 16 + kk) * 64 + lane) * 8);
          acc[nt2] = __builtin_amdgcn_mfma_f32_16x16x32_bf16(av, bv, acc[nt2], 0, 0, 0);
        }
      }
      // write out[b][t][col]; b = wv*16 + lkg*4 + i2, col = nt2*16 + lrow
      #pragma unroll
      for (int nt2 = 0; nt2 < 32; ++nt2) {
        #pragma unroll
        for (int i2 = 0; i2 < 4; ++i2) {
          int b = wv * 16 + lkg * 4 + i2;
          out[((long)b * T_ + t) * O_ + nt2 * 16 + lrow] = acc[nt2][i2];
        }
      }
    }

    // keep burning until the recurrence fully finishes (clock stability)
    #pragma unroll 1
    for (;;) {
      unsigned p;
      asm volatile("global_load_dword %0, %1, off sc0 sc1\n\ts_waitcnt vmcnt(0)"
                   : "=v"(p) : "v"((const unsigned int*)prog) : "memory");
      if ((int)p >= T_) break;
      #pragma unroll
      for (int u = 0; u < 512; ++u) burn = burn * 1.0000002f + 1e-9f;
      asm volatile("" : "+v"(burn));
    }
    if (burn == 1.2345e30f) out[0] = burn;   // keep burn live, never true
  }
  #undef KEEPPADS
}

// ---------------------------------------------------------------------------
extern "C" void kernel_launch(void* const* d_in, const int* in_sizes, int n_in,
                              void* d_out, int out_size, void* d_ws, size_t ws_size,
                              hipStream_t stream) {
  const float* x      = (const float*)d_in[0];
  const float* h_init = (const float*)d_in[1];
  const float* c_init = (const float*)d_in[2];
  const float* W_f = (const float*)d_in[3];
  const float* b_f = (const float*)d_in[4];
  const float* W_i = (const float*)d_in[5];
  const float* b_i = (const float*)d_in[6];
  const float* W_c = (const float*)d_in[7];
  const float* b_c = (const float*)d_in[8];
  const float* W_o = (const float*)d_in[9];
  const float* b_o = (const float*)d_in[10];
  const float* W_hy = (const float*)d_in[11];
  const float* b_hy = (const float*)d_in[12];
  float* out = (float*)d_out;

  // ws layout (bytes)
  const size_t WP_OFF   = 0;                          // 4 MB
  const size_t WHYP_OFF = 4u << 20;                   // 512 KB
  const size_t HBF0_OFF = WHYP_OFF + (512u << 10);    // 64 KB
  const size_t HBF1_OFF = HBF0_OFF + (64u << 10);     // 64 KB
  const size_t FLG_OFF  = HBF1_OFF + (64u << 10);     // flags/progress
  const size_t XB_OFF   = 8u << 20;                   // 64 MB (big path only)
  const size_t HS_BYTES = (size_t)T_ * B_ * H_ * 2;   // 64 MB
  const size_t XB_BYTES = (size_t)B_ * T_ * D_ * 2;   // 64 MB
  const size_t NEED_SMALL = (8u << 20) + HS_BYTES;
  const size_t NEED_BIG   = XB_OFF + XB_BYTES + HS_BYTES;
  if (ws_size < NEED_SMALL) return;
  const bool big = (ws_size >= NEED_BIG);

  unsigned char* w = (unsigned char*)d_ws;
  unsigned short* Wp   = (unsigned short*)(w + WP_OFF);
  unsigned short* Whyp = (unsigned short*)(w + WHYP_OFF);
  unsigned short* hbf0 = (unsigned short*)(w + HBF0_OFF);
  unsigned short* hbf1 = (unsigned short*)(w + HBF1_OFF);
  unsigned int*   flg  = (unsigned int*)(w + FLG_OFF);
  unsigned short* xb   = (unsigned short*)(w + XB_OFF);
  unsigned short* hs   = (unsigned short*)(w + (big ? XB_OFF + XB_BYTES : (size_t)(8u << 20)));

  // 1) pack weights + init + flag zeroing
  const long total = 1024L * 2048 + 512L * 512 + 64L * 512;
  int pgrid = (int)((total + 255) / 256);
  pack_setup<<<pgrid, 256, 0, stream>>>(W_f, W_i, W_c, W_o, W_hy, h_init,
                                        Wp, Whyp, hbf0, flg);

  // 2) optional x -> bf16 preconversion
  if (big) {
    const long nx = (long)B_ * T_ * D_;
    int xgrid = (int)(nx / (256 * 8));
    xconv<<<xgrid, 256, 0, stream>>>(x, xb);
  }

  // 3) fused recurrence + overlapped out_proj (256 blocks, all CUs busy)
  if (big) {
    lstm_fused<true><<<NBLK + NWORK, 256, 0, stream>>>(
        xb, c_init, b_f, b_i, b_c, b_o, Wp, Whyp, b_hy,
        hbf0, hbf1, hs, out, flg);
  } else {
    lstm_fused<false><<<NBLK + NWORK, 256, 0, stream>>>(
        x, c_init, b_f, b_i, b_c, b_o, Wp, Whyp, b_hy,
        hbf0, hbf1, hs, out, flg);
  }
}

// Round 8
// 15224.783 us; speedup vs baseline: 1.2928x; 1.2928x over previous
//
#include <hip/hip_runtime.h>
#include <hip/hip_bf16.h>

#define B_ 64
#define T_ 1024
#define D_ 512
#define H_ 512
#define O_ 512
#define NBLK 32        // j-slice blocks in recurrent kernel
#define FSTR 32        // flag stride in u32 (128 B = one cache line per flag)

using bf16x8 = __attribute__((ext_vector_type(8))) short;
using f32x4  = __attribute__((ext_vector_type(4))) float;

__device__ __forceinline__ short f2bfs(float f) {
  return (short)__builtin_bit_cast(unsigned short, __float2bfloat16(f));
}
__device__ __forceinline__ float sigmoid_f(float v) {
  return 1.0f / (1.0f + __expf(-v));
}
__device__ __forceinline__ float tanh_f(float v) {
  float a = fabsf(v);
  float e = __expf(-2.0f * a);
  float t = (1.0f - e) / (1.0f + e);
  return copysignf(t, v);
}

// ---------------------------------------------------------------------------
// Setup: pack W_all (1024x2048) and W_hy (512x512) into MFMA B-fragment order
// (bf16), convert h_init to bf16, zero the strided flags.
// ---------------------------------------------------------------------------
__global__ __launch_bounds__(256) void pack_setup(
    const float* __restrict__ Wf, const float* __restrict__ Wi,
    const float* __restrict__ Wc, const float* __restrict__ Wo,
    const float* __restrict__ Why, const float* __restrict__ hinit,
    unsigned short* __restrict__ Wp, unsigned short* __restrict__ Whyp,
    unsigned short* __restrict__ hbf0, unsigned int* __restrict__ flg)
{
  long idx = (long)blockIdx.x * blockDim.x + threadIdx.x;
  if (idx < NBLK * FSTR) flg[idx] = 0u;        // re-zeroed every call
  const long NW = 1024L * 2048;
  const long NY = 512L * 512;
  const long NH = 64L * 512;
  if (idx < NW) {
    int e = idx & 7, l = (idx >> 3) & 63, kk = (idx >> 9) & 31;
    int Jc = (int)(idx >> 14);                   // 0..127
    int k = kk * 32 + (l >> 4) * 8 + e;          // 0..1023
    int col = Jc * 16 + (l & 15);                // 0..2047
    int gg = col >> 9, j = col & 511;
    const float* W = (gg == 0) ? Wf : (gg == 1) ? Wi : (gg == 2) ? Wc : Wo;
    Wp[idx] = (unsigned short)f2bfs(W[(long)k * 512 + j]);
  } else if (idx < NW + NY) {
    long q = idx - NW;
    int e = q & 7, l = (q >> 3) & 63, kk = (q >> 9) & 15;
    int J = (int)(q >> 13);
    int k = kk * 32 + (l >> 4) * 8 + e;
    int col = J * 16 + (l & 15);
    Whyp[q] = (unsigned short)f2bfs(Why[(long)k * 512 + col]);
  } else if (idx < NW + NY + NH) {
    long q = idx - NW - NY;
    hbf0[q] = (unsigned short)f2bfs(hinit[q]);
  }
}

// ---------------------------------------------------------------------------
// x fp32 -> bf16 streaming conversion.
// ---------------------------------------------------------------------------
__global__ __launch_bounds__(256) void xconv(
    const float* __restrict__ x, unsigned short* __restrict__ xb)
{
  long i = ((long)blockIdx.x * 256 + threadIdx.x) * 8;
  float4 a = *(const float4*)(x + i);
  float4 b = *(const float4*)(x + i + 4);
  bf16x8 v;
  v[0] = f2bfs(a.x); v[1] = f2bfs(a.y); v[2] = f2bfs(a.z); v[3] = f2bfs(a.w);
  v[4] = f2bfs(b.x); v[5] = f2bfs(b.y); v[6] = f2bfs(b.z); v[7] = f2bfs(b.w);
  *(bf16x8*)(xb + i) = v;
}

// ---------------------------------------------------------------------------
// Sequential recurrence (round-4 proven data path + de-hot-lined flags).
// 32 blocks x 256 threads. Flags strided one per 128-B cache line:
//   - producer jb stores flg[jb*FSTR] (private line, no read backlog)
//   - consumer wave0 lane i polls flg[i*FSTR] (32 readers/line, paced)
// x-part MFMAs before the poll; h loads agent-coherent; publish sc0 sc1.
// ---------------------------------------------------------------------------
template<bool X16>
__global__ __launch_bounds__(256, 1) void lstm_seq(
    const void* __restrict__ xv,      // (B,T,D) bf16 or fp32
    const float* __restrict__ cinit,  // (B,H)
    const float* __restrict__ bf_, const float* __restrict__ bi_,
    const float* __restrict__ bc_, const float* __restrict__ bo_,
    const unsigned short* __restrict__ Wp,
    unsigned short* __restrict__ hbf0,
    unsigned short* __restrict__ hbf1,
    unsigned short* __restrict__ hs,  // (T,B,H) bf16
    float* __restrict__ tail,         // d_out + B*T*O : h_fin then c_fin
    unsigned int* __restrict__ flg)
{
  const int jb   = blockIdx.x;
  const int tid  = threadIdx.x;
  const int wv   = tid >> 6;
  const int lane = tid & 63;
  const int lrow = lane & 15;
  const int lkg  = lane >> 4;
  const int b_arow = wv * 16 + lrow;
  const int jcol   = jb * 16 + lrow;
  const int b_cd0  = wv * 16 + lkg * 4;

  const float vbf = bf_[jcol], vbi = bi_[jcol], vbc = bc_[jcol], vbo = bo_[jcol];
  float c0 = cinit[(long)(b_cd0 + 0) * H_ + jcol];
  float c1 = cinit[(long)(b_cd0 + 1) * H_ + jcol];
  float c2 = cinit[(long)(b_cd0 + 2) * H_ + jcol];
  float c3 = cinit[(long)(b_cd0 + 3) * H_ + jcol];

  const long aq = (long)b_arow * 128 + lkg * 2;   // u64 index into h buffers
  const unsigned short* xrow16 = X16 ? (const unsigned short*)xv + (long)b_arow * T_ * D_ + lkg * 8 : nullptr;
  const float*          xrow32 = X16 ? nullptr : (const float*)xv + (long)b_arow * T_ * D_ + lkg * 8;
  const unsigned short* w0 = Wp + (long)(0 * 32 + jb) * 32 * 512 + lane * 8;
  const unsigned short* w1 = Wp + (long)(1 * 32 + jb) * 32 * 512 + lane * 8;
  const unsigned short* w2 = Wp + (long)(2 * 32 + jb) * 32 * 512 + lane * 8;
  const unsigned short* w3 = Wp + (long)(3 * 32 + jb) * 32 * 512 + lane * 8;
  const unsigned long long* h0q = (const unsigned long long*)hbf0;
  const unsigned long long* h1q = (const unsigned long long*)hbf1;

  bf16x8 xf[16];
  float4 xr[32];
  if constexpr (X16) {
    #pragma unroll
    for (int kk = 0; kk < 16; ++kk) xf[kk] = *(const bf16x8*)(xrow16 + kk * 32);
  } else {
    #pragma unroll
    for (int kk = 0; kk < 16; ++kk) {
      xr[2*kk]   = *(const float4*)(xrow32 + kk * 32);
      xr[2*kk+1] = *(const float4*)(xrow32 + kk * 32 + 4);
    }
  }

  #pragma unroll 1
  for (int t = 0; t < T_; ++t) {
    // ---- x half of GEMM (k 512..1023) before the poll ----
    f32x4 af = {vbf, vbf, vbf, vbf};
    f32x4 ai = {vbi, vbi, vbi, vbi};
    f32x4 ac = {vbc, vbc, vbc, vbc};
    f32x4 ao = {vbo, vbo, vbo, vbo};
    #pragma unroll
    for (int kk = 0; kk < 16; ++kk) {
      bf16x8 ax;
      if constexpr (X16) {
        ax = xf[kk];
      } else {
        float4 xa = xr[2*kk], xb2 = xr[2*kk+1];
        ax[0]=f2bfs(xa.x); ax[1]=f2bfs(xa.y); ax[2]=f2bfs(xa.z); ax[3]=f2bfs(xa.w);
        ax[4]=f2bfs(xb2.x); ax[5]=f2bfs(xb2.y); ax[6]=f2bfs(xb2.z); ax[7]=f2bfs(xb2.w);
      }
      const int k2 = kk + 16;
      af = __builtin_amdgcn_mfma_f32_16x16x32_bf16(ax, *(const bf16x8*)(w0 + k2 * 512), af, 0, 0, 0);
      ai = __builtin_amdgcn_mfma_f32_16x16x32_bf16(ax, *(const bf16x8*)(w1 + k2 * 512), ai, 0, 0, 0);
      ac = __builtin_amdgcn_mfma_f32_16x16x32_bf16(ax, *(const bf16x8*)(w2 + k2 * 512), ac, 0, 0, 0);
      ao = __builtin_amdgcn_mfma_f32_16x16x32_bf16(ax, *(const bf16x8*)(w3 + k2 * 512), ao, 0, 0, 0);
    }

    // ---- handoff wait: wave0 only; each lane polls a PRIVATE flag line ----
    if (wv == 0) {
      const unsigned tgt = (unsigned)t;
      const unsigned int* fp = flg + (lane & 31) * FSTR;
      int guard = 0;
      for (;;) {
        unsigned f;
        asm volatile("global_load_dword %0, %1, off sc0 sc1\n\ts_waitcnt vmcnt(0)"
                     : "=v"(f) : "v"(fp) : "memory");
        if (__all((int)(f >= tgt))) break;
        if (++guard > (1 << 20)) break;
        __builtin_amdgcn_s_sleep(2);
      }
    }
    __syncthreads();
    asm volatile("" ::: "memory");

    // ---- h loads (agent-coherent u64) + h half of GEMM (k 0..511) ----
    const unsigned long long* hq = (t & 1) ? h1q : h0q;
    #pragma unroll
    for (int kk = 0; kk < 16; ++kk) {
      unsigned long long q0 = __hip_atomic_load(hq + aq + kk * 8,     __ATOMIC_RELAXED, __HIP_MEMORY_SCOPE_AGENT);
      unsigned long long q1 = __hip_atomic_load(hq + aq + kk * 8 + 1, __ATOMIC_RELAXED, __HIP_MEMORY_SCOPE_AGENT);
      union { unsigned long long q[2]; bf16x8 v; } u;
      u.q[0] = q0; u.q[1] = q1;
      bf16x8 ah = u.v;
      af = __builtin_amdgcn_mfma_f32_16x16x32_bf16(ah, *(const bf16x8*)(w0 + kk * 512), af, 0, 0, 0);
      ai = __builtin_amdgcn_mfma_f32_16x16x32_bf16(ah, *(const bf16x8*)(w1 + kk * 512), ai, 0, 0, 0);
      ac = __builtin_amdgcn_mfma_f32_16x16x32_bf16(ah, *(const bf16x8*)(w2 + kk * 512), ac, 0, 0, 0);
      ao = __builtin_amdgcn_mfma_f32_16x16x32_bf16(ah, *(const bf16x8*)(w3 + kk * 512), ao, 0, 0, 0);
    }

    // ---- gates + state update (C/D: col=lane&15, row=(lane>>4)*4+i) ----
    unsigned short* hw = (t & 1) ? hbf0 : hbf1;
    unsigned short hbv[4];
    float hvf[4], cvf[4];
    #pragma unroll
    for (int i2 = 0; i2 < 4; ++i2) {
      float fg = sigmoid_f(af[i2]);
      float ig = sigmoid_f(ai[i2]);
      float gg2 = tanh_f(ac[i2]);
      float og = sigmoid_f(ao[i2]);
      float cN = (i2 == 0) ? c0 : (i2 == 1) ? c1 : (i2 == 2) ? c2 : c3;
      cN = fg * cN + ig * gg2;
      float hv = og * tanh_f(cN);
      if (i2 == 0) c0 = cN; else if (i2 == 1) c1 = cN; else if (i2 == 2) c2 = cN; else c3 = cN;
      hvf[i2] = hv; cvf[i2] = cN;
      unsigned hb = (unsigned)(unsigned short)f2bfs(hv);
      hbv[i2] = (unsigned short)hb;
      unsigned short* hp2 = hw + (long)(b_cd0 + i2) * H_ + jcol;
      asm volatile("global_store_short %0, %1, off sc0 sc1" :: "v"(hp2), "v"(hb) : "memory");
    }

    // ---- drain publishes (barrier implies vmcnt(0)), then ONE flag store ----
    __syncthreads();
    asm volatile("" ::: "memory");
    if (tid == 0) {
      unsigned v = (unsigned)(t + 1);
      unsigned int* p2 = flg + jb * FSTR;     // private line
      asm volatile("global_store_dword %0, %1, off sc0 sc1" :: "v"(p2), "v"(v) : "memory");
    }
    asm volatile("" ::: "memory");

    // ---- off-critical-path: history, tail, next-x prefetch ----
    #pragma unroll
    for (int i2 = 0; i2 < 4; ++i2) {
      int brow = b_cd0 + i2;
      __builtin_nontemporal_store(hbv[i2], hs + ((long)t * B_ + brow) * H_ + jcol);
      if (t == T_ - 1) {
        tail[(long)brow * H_ + jcol] = hvf[i2];
        tail[(long)B_ * H_ + (long)brow * H_ + jcol] = cvf[i2];
      }
    }
    const long tn = (t + 1 < T_) ? (t + 1) : t;
    if constexpr (X16) {
      const unsigned short* xt = xrow16 + tn * D_;
      #pragma unroll
      for (int kk = 0; kk < 16; ++kk) xf[kk] = *(const bf16x8*)(xt + kk * 32);
    } else {
      const float* xt = xrow32 + tn * D_;
      #pragma unroll
      for (int kk = 0; kk < 16; ++kk) {
        xr[2*kk]   = *(const float4*)(xt + kk * 32);
        xr[2*kk+1] = *(const float4*)(xt + kk * 32 + 4);
      }
    }
  }
}

// ---------------------------------------------------------------------------
// Output projection: out(B,T,O) = hs(T,B,H) @ W_hy + b_hy.
// ---------------------------------------------------------------------------
__global__ __launch_bounds__(512) void out_proj(
    const unsigned short* __restrict__ hs,
    const unsigned short* __restrict__ Whyp,
    const float* __restrict__ bhy,
    float* __restrict__ out)
{
  const int tid  = threadIdx.x;
  const int wv   = tid >> 6;
  const int lane = tid & 63;
  const int lrow = lane & 15;
  const int lkg  = lane >> 4;
  const int mg = wv >> 2;
  const int ng = wv & 3;
  const long mbase = (long)blockIdx.x * 128 + mg * 64;

  f32x4 acc[4][8];
  #pragma unroll
  for (int mt = 0; mt < 4; ++mt)
    #pragma unroll
    for (int nt = 0; nt < 8; ++nt) {
      float b = bhy[ng * 128 + nt * 16 + lrow];
      acc[mt][nt] = {b, b, b, b};
    }

  const unsigned short* arow = hs + (mbase + lrow) * 512 + lkg * 8;
  const unsigned short* bbas = Whyp + (long)(ng * 8) * 8192 + lane * 8;

  #pragma unroll
  for (int kk = 0; kk < 16; ++kk) {
    bf16x8 a0 = *(const bf16x8*)(arow + 0 * 8192 + kk * 32);
    bf16x8 a1 = *(const bf16x8*)(arow + 1 * 8192 + kk * 32);
    bf16x8 a2 = *(const bf16x8*)(arow + 2 * 8192 + kk * 32);
    bf16x8 a3 = *(const bf16x8*)(arow + 3 * 8192 + kk * 32);
    #pragma unroll
    for (int nt = 0; nt < 8; ++nt) {
      bf16x8 bv = *(const bf16x8*)(bbas + nt * 8192 + kk * 512);
      acc[0][nt] = __builtin_amdgcn_mfma_f32_16x16x32_bf16(a0, bv, acc[0][nt], 0, 0, 0);
      acc[1][nt] = __builtin_amdgcn_mfma_f32_16x16x32_bf16(a1, bv, acc[1][nt], 0, 0, 0);
      acc[2][nt] = __builtin_amdgcn_mfma_f32_16x16x32_bf16(a2, bv, acc[2][nt], 0, 0, 0);
      acc[3][nt] = __builtin_amdgcn_mfma_f32_16x16x32_bf16(a3, bv, acc[3][nt], 0, 0, 0);
    }
  }

  #pragma unroll
  for (int mt = 0; mt < 4; ++mt) {
    #pragma unroll
    for (int i2 = 0; i2 < 4; ++i2) {
      long m = mbase + mt * 16 + lkg * 4 + i2;
      long t = m >> 6, b = m & 63;
      float* orow = out + (b * 1024 + t) * 512;
      #pragma unroll
      for (int nt = 0; nt < 8; ++nt)
        orow[ng * 128 + nt * 16 + lrow] = acc[mt][nt][i2];
    }
  }
}

// ---------------------------------------------------------------------------
extern "C" void kernel_launch(void* const* d_in, const int* in_sizes, int n_in,
                              void* d_out, int out_size, void* d_ws, size_t ws_size,
                              hipStream_t stream) {
  const float* x      = (const float*)d_in[0];
  const float* h_init = (const float*)d_in[1];
  const float* c_init = (const float*)d_in[2];
  const float* W_f = (const float*)d_in[3];
  const float* b_f = (const float*)d_in[4];
  const float* W_i = (const float*)d_in[5];
  const float* b_i = (const float*)d_in[6];
  const float* W_c = (const float*)d_in[7];
  const float* b_c = (const float*)d_in[8];
  const float* W_o = (const float*)d_in[9];
  const float* b_o = (const float*)d_in[10];
  const float* W_hy = (const float*)d_in[11];
  const float* b_hy = (const float*)d_in[12];
  float* out = (float*)d_out;

  // ws layout (bytes)
  const size_t WP_OFF   = 0;                          // 4 MB
  const size_t WHYP_OFF = 4u << 20;                   // 512 KB
  const size_t HBF0_OFF = WHYP_OFF + (512u << 10);    // 64 KB
  const size_t HBF1_OFF = HBF0_OFF + (64u << 10);     // 64 KB
  const size_t FLG_OFF  = HBF1_OFF + (64u << 10);     // 4 KB strided flags
  const size_t XB_OFF   = 8u << 20;                   // 64 MB (big path only)
  const size_t HS_BYTES = (size_t)T_ * B_ * H_ * 2;   // 64 MB
  const size_t XB_BYTES = (size_t)B_ * T_ * D_ * 2;   // 64 MB
  const size_t NEED_SMALL = (8u << 20) + HS_BYTES;
  const size_t NEED_BIG   = XB_OFF + XB_BYTES + HS_BYTES;
  if (ws_size < NEED_SMALL) return;
  const bool big = (ws_size >= NEED_BIG);

  unsigned char* w = (unsigned char*)d_ws;
  unsigned short* Wp   = (unsigned short*)(w + WP_OFF);
  unsigned short* Whyp = (unsigned short*)(w + WHYP_OFF);
  unsigned short* hbf0 = (unsigned short*)(w + HBF0_OFF);
  unsigned short* hbf1 = (unsigned short*)(w + HBF1_OFF);
  unsigned int*   flg  = (unsigned int*)(w + FLG_OFF);
  unsigned short* xb   = (unsigned short*)(w + XB_OFF);
  unsigned short* hs   = (unsigned short*)(w + (big ? XB_OFF + XB_BYTES : (size_t)(8u << 20)));

  // 1) pack weights + init + flag zeroing
  const long total = 1024L * 2048 + 512L * 512 + 64L * 512;
  int pgrid = (int)((total + 255) / 256);
  pack_setup<<<pgrid, 256, 0, stream>>>(W_f, W_i, W_c, W_o, W_hy, h_init,
                                        Wp, Whyp, hbf0, flg);

  // 2) optional x -> bf16 preconversion
  if (big) {
    const long nx = (long)B_ * T_ * D_;
    int xgrid = (int)(nx / (256 * 8));
    xconv<<<xgrid, 256, 0, stream>>>(x, xb);
  }

  // 3) sequential recurrence (de-hot-lined flags)
  float* tail = out + (size_t)B_ * T_ * O_;
  if (big) {
    lstm_seq<true><<<NBLK, 256, 0, stream>>>(xb, c_init, b_f, b_i, b_c, b_o,
                                             Wp, hbf0, hbf1, hs, tail, flg);
  } else {
    lstm_seq<false><<<NBLK, 256, 0, stream>>>(x, c_init, b_f, b_i, b_c, b_o,
                                              Wp, hbf0, hbf1, hs, tail, flg);
  }

  // 4) output projection
  out_proj<<<512, 512, 0, stream>>>(hs, Whyp, b_hy, out);
}